// Round 13
// baseline (26.090 us; speedup 1.0000x reference)
//
#include <hip/hip_runtime.h>

#define NCH 1024      // OUT_CH * IN_GROUP
#define KHW 64        // H*W = GEMM K
#define BPT 128       // points per block
#define BCH 128       // channels per block
#define WST 72        // Wl row stride in bf16 (144 B, 16B-aligned)
#define CST 72        // Cl row stride in bf16

typedef __attribute__((ext_vector_type(8))) short          bf16x8;
typedef __attribute__((ext_vector_type(4))) float          f32x4;
typedef __attribute__((ext_vector_type(4))) int            i32x4;
typedef __attribute__((ext_vector_type(4))) unsigned short u16x4;

__device__ __forceinline__ unsigned short f2bf(float f) {
    unsigned int u = __float_as_uint(f);
    u += 0x7FFFu + ((u >> 16) & 1u);          // round-to-nearest-even
    return (unsigned short)(u >> 16);
}

__global__ __launch_bounds__(256, 4)
void spline_gemm(const float* __restrict__ xy,
                 const float* __restrict__ C,
                 const float* __restrict__ Tx,
                 const float* __restrict__ Ty,
                 float* __restrict__ out,
                 int npts, int ntx, int nty) {
    __shared__ __align__(16) unsigned short Cl[BCH * CST];   // 18 KB C slice (bf16)
    __shared__ __align__(16) unsigned short Wl[BPT * WST];   // 18 KB point weights

    const int t     = threadIdx.x;
    const int cgrp  = blockIdx.x & 7;      // 8 channel groups -> XCD-pinned
    const int pgrp  = blockIdx.x >> 3;     // 128 point groups of 128 points
    const int pbase = pgrp * BPT;
    const int cbase = cgrp * BCH;

    // ---- role-split prologue: t<128 weights  ||  t>=128 C-stage ----
    if (t < BPT) {
        const int n  = pbase + t;
        const int nc = min(n, npts - 1);
        float2 p = *(const float2*)(xy + 2 * nc);
        float X = p.x, Y = p.y;

        int kx = 2;
        for (int i = 3; i <= ntx - 4; ++i) kx += (Tx[i] <= X) ? 1 : 0;
        int ky = 2;
        for (int i = 3; i <= nty - 4; ++i) ky += (Ty[i] <= Y) ? 1 : 0;

        float tkm1 = Tx[kx - 1], tk = Tx[kx], tk1 = Tx[kx + 1], tk2 = Tx[kx + 2];
        float d;
        d = tk1 - tkm1; float a10 = (X - tkm1) / (d == 0.f ? 1.f : d);
        d = tk2 - tk;   float a11 = (X - tk)   / (d == 0.f ? 1.f : d);
        d = tk1 - tk;   float a21 = (X - tk)   / (d == 0.f ? 1.f : d);
        float wx0 = (1.f - a21) * (1.f - a10);
        float wx1 = (1.f - a21) * a10 + a21 * (1.f - a11);
        float wx2 = a21 * a11;

        tkm1 = Ty[ky - 1]; tk = Ty[ky]; tk1 = Ty[ky + 1]; tk2 = Ty[ky + 2];
        d = tk1 - tkm1; float b10 = (Y - tkm1) / (d == 0.f ? 1.f : d);
        d = tk2 - tk;   float b11 = (Y - tk)   / (d == 0.f ? 1.f : d);
        d = tk1 - tk;   float b21 = (Y - tk)   / (d == 0.f ? 1.f : d);
        float wy0 = (1.f - b21) * (1.f - b10);
        float wy1 = (1.f - b21) * b10 + b21 * (1.f - b11);
        float wy2 = b21 * b11;

        unsigned short* rowbase = &Wl[t * WST];
        i32x4 z = {0, 0, 0, 0};
        #pragma unroll
        for (int j = 0; j < 8; ++j) *(i32x4*)(rowbase + j * 8) = z;

        unsigned short* row = rowbase + (kx - 2) * 8 + (ky - 2);
        row[0]  = f2bf(wx0 * wy0); row[1]  = f2bf(wx0 * wy1); row[2]  = f2bf(wx0 * wy2);
        row[8]  = f2bf(wx1 * wy0); row[9]  = f2bf(wx1 * wy1); row[10] = f2bf(wx1 * wy2);
        row[16] = f2bf(wx2 * wy0); row[17] = f2bf(wx2 * wy1); row[18] = f2bf(wx2 * wy2);
    } else {
        const int tt = t - BPT;
        const float* Cb = C + (size_t)cbase * KHW;
        #pragma unroll
        for (int r = 0; r < 16; ++r) {
            const int fi = r * 512 + tt * 4;
            f32x4 v = *(const f32x4*)(Cb + fi);
            const int ch = fi >> 6, k = fi & 63;
            u16x4 w;
            w.x = f2bf(v.x); w.y = f2bf(v.y); w.z = f2bf(v.z); w.w = f2bf(v.w);
            *(u16x4*)&Cl[ch * CST + k] = w;
        }
    }
    __syncthreads();   // the ONLY barrier

    // ---- STAGGER: spread store-phase entry across ~7.5us in 4 cohorts ----
    // s_sleep(94) ~ 6016 cycles ~ 2.5us; deterministic instruction stream,
    // output identical. Tests the "chip-wide store burst overwhelms the
    // sink" hypothesis: sink fed continuously instead of one 67MB spike.
    {
        const int cohort = (blockIdx.x >> 3) & 3;
        for (int s = 0; s < cohort; ++s)
            __builtin_amdgcn_s_sleep(94);
    }

    // ---- 4 waves: wm = ch half (64), wn = pt half (64); 32 MFMA + 16 stores ----
    const int wid  = t >> 6;
    const int lane = t & 63;
    const int wm   = wid & 1;
    const int wn   = wid >> 1;
    const int l15  = lane & 15;
    const int l4   = lane >> 4;

    const unsigned short* Ab = Cl + (wm * 64 + l15) * CST + l4 * 8;
    const unsigned short* Bb = Wl + (wn * 64 + l15) * WST + l4 * 8;

    f32x4 acc[4][4] = {};
    #pragma unroll
    for (int kr = 0; kr < 2; ++kr) {
        bf16x8 a[4], b[4];
        #pragma unroll
        for (int mf = 0; mf < 4; ++mf) a[mf] = *(const bf16x8*)(Ab + mf * 16 * CST + kr * 32);
        #pragma unroll
        for (int nf = 0; nf < 4; ++nf) b[nf] = *(const bf16x8*)(Bb + nf * 16 * WST + kr * 32);
        #pragma unroll
        for (int mf = 0; mf < 4; ++mf)
            #pragma unroll
            for (int nf = 0; nf < 4; ++nf)
                acc[mf][nf] = __builtin_amdgcn_mfma_f32_16x16x32_bf16(
                                  a[mf], b[nf], acc[mf][nf], 0, 0, 0);
    }

    // ---- stores: lane's 4 acc regs = 4 consecutive channels -> dwordx4 ----
    #pragma unroll
    for (int nf = 0; nf < 4; ++nf) {
        const int pt = pbase + wn * 64 + nf * 16 + l15;
        float* op = out + (size_t)pt * NCH + cbase + wm * 64 + l4 * 4;
        if (pt < npts) {
            #pragma unroll
            for (int mf = 0; mf < 4; ++mf)
                *(f32x4*)(op + mf * 16) = acc[mf][nf];
        }
    }
}

extern "C" void kernel_launch(void* const* d_in, const int* in_sizes, int n_in,
                              void* d_out, int out_size, void* d_ws, size_t ws_size,
                              hipStream_t stream) {
    const float* xy = (const float*)d_in[0];
    const float* C  = (const float*)d_in[1];
    const float* Tx = (const float*)d_in[2];
    const float* Ty = (const float*)d_in[3];
    float* out = (float*)d_out;

    int npts = in_sizes[0] / 2;
    int ntx  = in_sizes[2];
    int nty  = in_sizes[3];

    int pgs = (npts + BPT - 1) / BPT;
    dim3 grid(pgs * 8);
    dim3 block(256);
    hipLaunchKernelGGL(spline_gemm, grid, block, 0, stream,
                       xy, C, Tx, Ty, out, npts, ntx, nty);
}

// Round 14
// 22.317 us; speedup vs baseline: 1.1691x; 1.1691x over previous
//
#include <hip/hip_runtime.h>

#define NCH 1024      // OUT_CH * IN_GROUP
#define KHW 64        // H*W = GEMM K
#define BPT 128       // points per block
#define BCH 128       // channels per block
#define WST 72        // Wl row stride in bf16 (144 B, 16B-aligned)
#define CST 72        // Cl row stride in bf16
#define SROW 132      // stage row stride in f32 words (528 B, 16B-aligned)

typedef __attribute__((ext_vector_type(8))) short          bf16x8;
typedef __attribute__((ext_vector_type(4))) float          f32x4;
typedef __attribute__((ext_vector_type(4))) int            i32x4;
typedef __attribute__((ext_vector_type(4))) unsigned short u16x4;

__device__ __forceinline__ unsigned short f2bf(float f) {
    unsigned int u = __float_as_uint(f);
    u += 0x7FFFu + ((u >> 16) & 1u);          // round-to-nearest-even
    return (unsigned short)(u >> 16);
}

__global__ __launch_bounds__(256, 4)
void spline_gemm(const float* __restrict__ xy,
                 const float* __restrict__ C,
                 const float* __restrict__ Tx,
                 const float* __restrict__ Ty,
                 float* __restrict__ out,
                 int npts, int ntx, int nty) {
    // 36 KB shared: Cl+Wl during GEMM; reused as the transpose stage after.
    __shared__ __align__(16) unsigned char lds_buf[BCH * CST * 2 + BPT * WST * 2];
    unsigned short* Cl    = (unsigned short*)lds_buf;
    unsigned short* Wl    = (unsigned short*)(lds_buf + BCH * CST * 2);
    float*          stage = (float*)lds_buf;           // 64 pts x 132 words = 33792 B

    const int t     = threadIdx.x;
    const int cgrp  = blockIdx.x & 7;      // 8 channel groups -> XCD-pinned
    const int pgrp  = blockIdx.x >> 3;     // 128 point groups of 128 points
    const int pbase = pgrp * BPT;
    const int cbase = cgrp * BCH;

    // ---- role-split prologue: t<128 weights  ||  t>=128 C-stage ----
    if (t < BPT) {
        const int n  = pbase + t;
        const int nc = min(n, npts - 1);
        float2 p = *(const float2*)(xy + 2 * nc);
        float X = p.x, Y = p.y;

        int kx = 2;
        for (int i = 3; i <= ntx - 4; ++i) kx += (Tx[i] <= X) ? 1 : 0;
        int ky = 2;
        for (int i = 3; i <= nty - 4; ++i) ky += (Ty[i] <= Y) ? 1 : 0;

        float tkm1 = Tx[kx - 1], tk = Tx[kx], tk1 = Tx[kx + 1], tk2 = Tx[kx + 2];
        float d;
        d = tk1 - tkm1; float a10 = (X - tkm1) / (d == 0.f ? 1.f : d);
        d = tk2 - tk;   float a11 = (X - tk)   / (d == 0.f ? 1.f : d);
        d = tk1 - tk;   float a21 = (X - tk)   / (d == 0.f ? 1.f : d);
        float wx0 = (1.f - a21) * (1.f - a10);
        float wx1 = (1.f - a21) * a10 + a21 * (1.f - a11);
        float wx2 = a21 * a11;

        tkm1 = Ty[ky - 1]; tk = Ty[ky]; tk1 = Ty[ky + 1]; tk2 = Ty[ky + 2];
        d = tk1 - tkm1; float b10 = (Y - tkm1) / (d == 0.f ? 1.f : d);
        d = tk2 - tk;   float b11 = (Y - tk)   / (d == 0.f ? 1.f : d);
        d = tk1 - tk;   float b21 = (Y - tk)   / (d == 0.f ? 1.f : d);
        float wy0 = (1.f - b21) * (1.f - b10);
        float wy1 = (1.f - b21) * b10 + b21 * (1.f - b11);
        float wy2 = b21 * b11;

        unsigned short* rowbase = &Wl[t * WST];
        i32x4 z = {0, 0, 0, 0};
        #pragma unroll
        for (int j = 0; j < 8; ++j) *(i32x4*)(rowbase + j * 8) = z;

        unsigned short* row = rowbase + (kx - 2) * 8 + (ky - 2);
        row[0]  = f2bf(wx0 * wy0); row[1]  = f2bf(wx0 * wy1); row[2]  = f2bf(wx0 * wy2);
        row[8]  = f2bf(wx1 * wy0); row[9]  = f2bf(wx1 * wy1); row[10] = f2bf(wx1 * wy2);
        row[16] = f2bf(wx2 * wy0); row[17] = f2bf(wx2 * wy1); row[18] = f2bf(wx2 * wy2);
    } else {
        const int tt = t - BPT;
        const float* Cb = C + (size_t)cbase * KHW;
        #pragma unroll
        for (int r = 0; r < 16; ++r) {
            const int fi = r * 512 + tt * 4;
            f32x4 v = *(const f32x4*)(Cb + fi);
            const int ch = fi >> 6, k = fi & 63;
            u16x4 w;
            w.x = f2bf(v.x); w.y = f2bf(v.y); w.z = f2bf(v.z); w.w = f2bf(v.w);
            *(u16x4*)&Cl[ch * CST + k] = w;
        }
    }
    __syncthreads();                                   // barrier 1: Cl/Wl ready

    // ---- 4 waves: wm = ch half (64), wn = pt half (64) ----
    const int wid  = t >> 6;
    const int lane = t & 63;
    const int wm   = wid & 1;
    const int wn   = wid >> 1;
    const int l15  = lane & 15;
    const int l4   = lane >> 4;

    const unsigned short* Ab = Cl + (wm * 64 + l15) * CST + l4 * 8;
    const unsigned short* Bb = Wl + (wn * 64 + l15) * WST + l4 * 8;

    f32x4 acc[4][4] = {};
    #pragma unroll
    for (int kr = 0; kr < 2; ++kr) {
        bf16x8 a[4], b[4];
        #pragma unroll
        for (int mf = 0; mf < 4; ++mf) a[mf] = *(const bf16x8*)(Ab + mf * 16 * CST + kr * 32);
        #pragma unroll
        for (int nf = 0; nf < 4; ++nf) b[nf] = *(const bf16x8*)(Bb + nf * 16 * WST + kr * 32);
        #pragma unroll
        for (int mf = 0; mf < 4; ++mf)
            #pragma unroll
            for (int nf = 0; nf < 4; ++nf)
                acc[mf][nf] = __builtin_amdgcn_mfma_f32_16x16x32_bf16(
                                  a[mf], b[nf], acc[mf][nf], 0, 0, 0);
    }
    __syncthreads();                                   // barrier 2: Cl/Wl dead

    // ---- two half-tiles: stage 64 pts x 128 ch, then contiguous stores ----
    #pragma unroll
    for (int half = 0; half < 2; ++half) {
        if (wn == half) {
            // owning waves write acc -> stage (ds_write_b128)
            // D layout: col(l15)=point, row(l4*4+reg)=channel
            #pragma unroll
            for (int nf = 0; nf < 4; ++nf) {
                const int lp = nf * 16 + l15;          // 0..63 within half
                float* sp = stage + lp * SROW + wm * 64 + l4 * 4;
                #pragma unroll
                for (int mf = 0; mf < 4; ++mf)
                    *(f32x4*)(sp + mf * 16) = acc[mf][nf];
            }
        }
        __syncthreads();                               // stage ready

        // all waves: stream 512B-contiguous runs (2 pts per instruction)
        #pragma unroll
        for (int q = 0; q < 8; ++q) {
            const int lp = wid * 16 + q * 2 + (lane >> 5);   // 0..63
            const int pt = pbase + half * 64 + lp;
            f32x4 v = *(const f32x4*)(stage + lp * SROW + (lane & 31) * 4);
            if (pt < npts)
                *(f32x4*)(out + (size_t)pt * NCH + cbase + (lane & 31) * 4) = v;
        }
        __syncthreads();                               // stage reads done
    }
}

extern "C" void kernel_launch(void* const* d_in, const int* in_sizes, int n_in,
                              void* d_out, int out_size, void* d_ws, size_t ws_size,
                              hipStream_t stream) {
    const float* xy = (const float*)d_in[0];
    const float* C  = (const float*)d_in[1];
    const float* Tx = (const float*)d_in[2];
    const float* Ty = (const float*)d_in[3];
    float* out = (float*)d_out;

    int npts = in_sizes[0] / 2;
    int ntx  = in_sizes[2];
    int nty  = in_sizes[3];

    int pgs = (npts + BPT - 1) / BPT;
    dim3 grid(pgs * 8);
    dim3 block(256);
    hipLaunchKernelGGL(spline_gemm, grid, block, 0, stream,
                       xy, C, Tx, Ty, out, npts, ntx, nty);
}

// Round 15
// 19.763 us; speedup vs baseline: 1.3201x; 1.1292x over previous
//
#include <hip/hip_runtime.h>

#define NCH 1024      // OUT_CH * IN_GROUP
#define KHW 64        // H*W = GEMM K
#define BPT 128       // points per block
#define BCH 128       // channels per block
#define WST 72        // Wl row stride in bf16 (144 B, 16B-aligned)
#define CST 72        // Cl row stride in bf16

typedef __attribute__((ext_vector_type(8))) short          bf16x8;
typedef __attribute__((ext_vector_type(4))) float          f32x4;
typedef __attribute__((ext_vector_type(4))) int            i32x4;
typedef __attribute__((ext_vector_type(4))) unsigned short u16x4;

__device__ __forceinline__ unsigned short f2bf(float f) {
    unsigned int u = __float_as_uint(f);
    u += 0x7FFFu + ((u >> 16) & 1u);          // round-to-nearest-even
    return (unsigned short)(u >> 16);
}

__global__ __launch_bounds__(256, 4)
void spline_gemm(const float* __restrict__ xy,
                 const float* __restrict__ C,
                 const float* __restrict__ Tx,
                 const float* __restrict__ Ty,
                 float* __restrict__ out,
                 int npts, int ntx, int nty) {
    __shared__ __align__(16) unsigned short Cl[BCH * CST];   // 18 KB C slice (bf16)
    __shared__ __align__(16) unsigned short Wl[BPT * WST];   // 18 KB point weights

    const int t     = threadIdx.x;
    const int cgrp  = blockIdx.x & 7;      // 8 channel groups -> XCD-pinned
    const int pgrp  = blockIdx.x >> 3;     // 128 point groups of 128 points
    const int pbase = pgrp * BPT;
    const int cbase = cgrp * BCH;

    // ---- role-split prologue: t<128 weights  ||  t>=128 C-stage ----
    if (t < BPT) {
        // per-point quadratic B-spline weights, one point per thread
        const int n  = pbase + t;
        const int nc = min(n, npts - 1);
        float2 p = *(const float2*)(xy + 2 * nc);
        float X = p.x, Y = p.y;

        int kx = 2;
        for (int i = 3; i <= ntx - 4; ++i) kx += (Tx[i] <= X) ? 1 : 0;
        int ky = 2;
        for (int i = 3; i <= nty - 4; ++i) ky += (Ty[i] <= Y) ? 1 : 0;

        float tkm1 = Tx[kx - 1], tk = Tx[kx], tk1 = Tx[kx + 1], tk2 = Tx[kx + 2];
        float d;
        d = tk1 - tkm1; float a10 = (X - tkm1) / (d == 0.f ? 1.f : d);
        d = tk2 - tk;   float a11 = (X - tk)   / (d == 0.f ? 1.f : d);
        d = tk1 - tk;   float a21 = (X - tk)   / (d == 0.f ? 1.f : d);
        float wx0 = (1.f - a21) * (1.f - a10);
        float wx1 = (1.f - a21) * a10 + a21 * (1.f - a11);
        float wx2 = a21 * a11;

        tkm1 = Ty[ky - 1]; tk = Ty[ky]; tk1 = Ty[ky + 1]; tk2 = Ty[ky + 2];
        d = tk1 - tkm1; float b10 = (Y - tkm1) / (d == 0.f ? 1.f : d);
        d = tk2 - tk;   float b11 = (Y - tk)   / (d == 0.f ? 1.f : d);
        d = tk1 - tk;   float b21 = (Y - tk)   / (d == 0.f ? 1.f : d);
        float wy0 = (1.f - b21) * (1.f - b10);
        float wy1 = (1.f - b21) * b10 + b21 * (1.f - b11);
        float wy2 = b21 * b11;

        // zero own row (8 x 16B) then scatter the 9 taps
        unsigned short* rowbase = &Wl[t * WST];
        i32x4 z = {0, 0, 0, 0};
        #pragma unroll
        for (int j = 0; j < 8; ++j) *(i32x4*)(rowbase + j * 8) = z;

        unsigned short* row = rowbase + (kx - 2) * 8 + (ky - 2);
        row[0]  = f2bf(wx0 * wy0); row[1]  = f2bf(wx0 * wy1); row[2]  = f2bf(wx0 * wy2);
        row[8]  = f2bf(wx1 * wy0); row[9]  = f2bf(wx1 * wy1); row[10] = f2bf(wx1 * wy2);
        row[16] = f2bf(wx2 * wy0); row[17] = f2bf(wx2 * wy1); row[18] = f2bf(wx2 * wy2);
    } else {
        // stage C slice (128 ch x 64 k = 8192 floats) -> bf16 LDS, 64 floats/thread
        const int tt = t - BPT;
        const float* Cb = C + (size_t)cbase * KHW;
        #pragma unroll
        for (int r = 0; r < 16; ++r) {
            const int fi = r * 512 + tt * 4;
            f32x4 v = *(const f32x4*)(Cb + fi);
            const int ch = fi >> 6, k = fi & 63;
            u16x4 w;
            w.x = f2bf(v.x); w.y = f2bf(v.y); w.z = f2bf(v.z); w.w = f2bf(v.w);
            *(u16x4*)&Cl[ch * CST + k] = w;
        }
    }
    __syncthreads();   // the ONLY barrier

    // ---- 4 waves: wm = ch half (64), wn = pt half (64); 32 MFMA + 16 stores ----
    const int wid  = t >> 6;
    const int lane = t & 63;
    const int wm   = wid & 1;
    const int wn   = wid >> 1;
    const int l15  = lane & 15;
    const int l4   = lane >> 4;

    const unsigned short* Ab = Cl + (wm * 64 + l15) * CST + l4 * 8;
    const unsigned short* Bb = Wl + (wn * 64 + l15) * WST + l4 * 8;

    f32x4 acc[4][4] = {};
    #pragma unroll
    for (int kr = 0; kr < 2; ++kr) {
        bf16x8 a[4], b[4];
        #pragma unroll
        for (int mf = 0; mf < 4; ++mf) a[mf] = *(const bf16x8*)(Ab + mf * 16 * CST + kr * 32);
        #pragma unroll
        for (int nf = 0; nf < 4; ++nf) b[nf] = *(const bf16x8*)(Bb + nf * 16 * WST + kr * 32);
        #pragma unroll
        for (int mf = 0; mf < 4; ++mf)
            #pragma unroll
            for (int nf = 0; nf < 4; ++nf)
                acc[mf][nf] = __builtin_amdgcn_mfma_f32_16x16x32_bf16(
                                  a[mf], b[nf], acc[mf][nf], 0, 0, 0);
    }

    // ---- stores: lane's 4 acc regs = 4 consecutive channels -> dwordx4 ----
    #pragma unroll
    for (int nf = 0; nf < 4; ++nf) {
        const int pt = pbase + wn * 64 + nf * 16 + l15;
        float* op = out + (size_t)pt * NCH + cbase + wm * 64 + l4 * 4;
        if (pt < npts) {
            #pragma unroll
            for (int mf = 0; mf < 4; ++mf)
                *(f32x4*)(op + mf * 16) = acc[mf][nf];
        }
    }
}

extern "C" void kernel_launch(void* const* d_in, const int* in_sizes, int n_in,
                              void* d_out, int out_size, void* d_ws, size_t ws_size,
                              hipStream_t stream) {
    const float* xy = (const float*)d_in[0];
    const float* C  = (const float*)d_in[1];
    const float* Tx = (const float*)d_in[2];
    const float* Ty = (const float*)d_in[3];
    float* out = (float*)d_out;

    int npts = in_sizes[0] / 2;
    int ntx  = in_sizes[2];
    int nty  = in_sizes[3];

    int pgs = (npts + BPT - 1) / BPT;
    dim3 grid(pgs * 8);
    dim3 block(256);
    hipLaunchKernelGGL(spline_gemm, grid, block, 0, stream,
                       xy, C, Tx, Ty, out, npts, ntx, nty);
}